// Round 9
// baseline (2219.976 us; speedup 1.0000x reference)
//
#include <hip/hip_runtime.h>

typedef unsigned short u16;

#define NEG_SLOPE 0.2f

static __device__ __forceinline__ float b2f(u16 u) {
    union { unsigned int i; float f; } x; x.i = ((unsigned int)u) << 16; return x.f;
}
static __device__ __forceinline__ u16 f2b(float f) {
    unsigned int u = __float_as_uint(f);
    unsigned int r = (u + 0x7fffu + ((u >> 16) & 1u)) >> 16;
    return (u16)r;
}

// ---------------------------------------------------------------------------
// diagnostics (fp32 output now)
// code 32: CSR inconsistent ; code 64: non-finite final out ; 1000+: ws small
// ---------------------------------------------------------------------------
__global__ void k_diag(float* out, int n, float val)
{
    int i = blockIdx.x * 256 + threadIdx.x;
    if (i < n) out[i] = val;
}

__global__ void scan_csr(const int* off, const int* srcs, int N, int E,
                         int* flag, int bit)
{
    int i = blockIdx.x * 256 + threadIdx.x;
    if (i < N) {
        int a = off[i], b = off[i + 1];
        if (a < 0 || b < a || b > E) atomicOr(flag, bit);
    }
    if (i == 0 && off[N] != E) atomicOr(flag, bit);
    if (i < E) {
        if ((unsigned)srcs[i] >= (unsigned)N) atomicOr(flag, bit);
    }
}

__global__ void scan_out(const float* buf, int n, int* flag, int bit)
{
    int i = blockIdx.x * 256 + threadIdx.x;
    if (i < n) {
        float v = buf[i];
        if (!(v == v) || fabsf(v) > 1e30f) atomicOr(flag, bit);
    }
}

__global__ void k_final_diag(const int* flag, float* out, int n)
{
    int f = *flag;
    if (f == 0) return;
    int b = __ffs(f) - 1;
    float val = 32.0f * (b + 1);
    int i = blockIdx.x * 256 + threadIdx.x;
    if (i < n) out[i] = val;
}

// ---------------------------------------------------------------------------
// edge_index dtype probe + canonical int32 extraction
// ---------------------------------------------------------------------------
__global__ void k_detect(const int* ei, int E, int* flag64)
{
    __shared__ int zc;
    if (threadIdx.x == 0) zc = 0;
    __syncthreads();
    int idx = 1 + 2 * (int)threadIdx.x;
    int z = (idx < 2 * E && ei[idx] == 0) ? 1 : 0;
    atomicAdd(&zc, z);
    __syncthreads();
    if (threadIdx.x == 0) *flag64 = (zc >= 200) ? 1 : 0;
}

__global__ void k_extract(const int* ei, int E, const int* flag64,
                          int* src, int* dst)
{
    int e = blockIdx.x * 256 + threadIdx.x;
    if (e >= E) return;
    if (*flag64) {
        src[e] = ei[2 * e];
        dst[e] = ei[2 * E + 2 * e];
    } else {
        src[e] = ei[e];
        dst[e] = ei[E + e];
    }
}

// ---------------------------------------------------------------------------
// CSR construction (bound-checked)
// ---------------------------------------------------------------------------
__global__ void k_count(const int* dst, int* deg, int E, int N)
{
    int e = blockIdx.x * 256 + threadIdx.x;
    if (e < E) {
        int d = dst[e];
        if ((unsigned)d < (unsigned)N) atomicAdd(&deg[d], 1);
    }
}

__global__ __launch_bounds__(1024)
void k_scan(const int* deg, int* off, int* cursor, int N, int E)
{
    __shared__ int sd[1024];
    __shared__ int running;
    int tid = threadIdx.x;
    if (tid == 0) running = 0;
    __syncthreads();
    for (int base = 0; base < N; base += 1024) {
        int i = base + tid;
        int v = (i < N) ? deg[i] : 0;
        sd[tid] = v;
        __syncthreads();
        for (int s = 1; s < 1024; s <<= 1) {
            int t = (tid >= s) ? sd[tid - s] : 0;
            __syncthreads();
            sd[tid] += t;
            __syncthreads();
        }
        int excl = sd[tid] - v + running;
        if (i < N) { off[i] = excl; cursor[i] = excl; }
        int total = sd[1023];
        __syncthreads();
        if (tid == 0) running += total;
        __syncthreads();
    }
    if (tid == 0) off[N] = E;
}

__global__ void k_scatter(const int* src, const int* dst, int* cursor,
                          int* srcs, int E, int N)
{
    int e = blockIdx.x * 256 + threadIdx.x;
    if (e < E) {
        int d = dst[e];
        if ((unsigned)d < (unsigned)N) {
            int p = atomicAdd(&cursor[d], 1);
            if ((unsigned)p < (unsigned)E) srcs[p] = src[e];
        }
    }
}

// ---------------------------------------------------------------------------
// direct row-dot on bf16 h against two fp32 vectors — one wave per node
// ---------------------------------------------------------------------------
__global__ __launch_bounds__(256)
void k_rowdot2(const u16* h, int ld, int H, const float* vs, const float* vd,
               float* a_s, float* a_d, int N)
{
    int wave = threadIdx.x >> 6, lane = threadIdx.x & 63;
    int n = blockIdx.x * 4 + wave;
    if (n >= N) return;
    const u16* hr = h + (size_t)n * ld;
    float ss = 0.f, sd = 0.f;
    for (int i = lane; i < H; i += 64) {
        float v = b2f(hr[i]);
        ss += v * vs[i];
        sd += v * vd[i];
    }
    #pragma unroll
    for (int m = 32; m; m >>= 1) {
        ss += __shfl_xor(ss, m, 64);
        sd += __shfl_xor(sd, m, 64);
    }
    if (lane == 0) { a_s[n] = ss; a_d[n] = sd; }
}

// ---------------------------------------------------------------------------
// per-dst softmax stats
// ---------------------------------------------------------------------------
__global__ __launch_bounds__(256)
void k_alpha(const int* off, const int* srcs, const float* a_s, const float* a_d,
             float* mx, float* ssum, int N)
{
    int wave = threadIdx.x >> 6, lane = threadIdx.x & 63;
    int n = blockIdx.x * 4 + wave;
    if (n >= N) return;
    int base = off[n], end = off[n + 1];
    float adn = a_d[n];
    float m = -1e30f;
    for (int p = base + lane; p < end; p += 64) {
        int s = srcs[p];
        s = ((unsigned)s < (unsigned)N) ? s : 0;
        float z = a_s[s] + adn;
        z = z > 0.f ? z : NEG_SLOPE * z;
        m = fmaxf(m, z);
    }
    #pragma unroll
    for (int s = 32; s; s >>= 1) m = fmaxf(m, __shfl_xor(m, s, 64));
    float sum = 0.f;
    for (int p = base + lane; p < end; p += 64) {
        int s = srcs[p];
        s = ((unsigned)s < (unsigned)N) ? s : 0;
        float z = a_s[s] + adn;
        z = z > 0.f ? z : NEG_SLOPE * z;
        sum += __expf(z - m);
    }
    #pragma unroll
    for (int s = 32; s; s >>= 1) sum += __shfl_xor(sum, s, 64);
    if (lane == 0) { mx[n] = m; ssum[n] = sum; }
}

// ---------------------------------------------------------------------------
// layer-1 aggregation, 512-wide: hl1 = relu(agg(h1)/ssum + pre), in-place pre
// ---------------------------------------------------------------------------
__global__ __launch_bounds__(256)
void k_agg1(const u16* h1, const int* off, const int* srcs,
            const float* a_s, const float* a_d, const float* mx, const float* ssum,
            u16* hl1, int N)
{
    int n = blockIdx.x;
    int base = off[n], end = off[n + 1];
    float adn = a_d[n], mn = mx[n];
    float inv = 1.f / (ssum[n] + 1e-16f);
    int c = threadIdx.x;
    float acc0 = 0.f, acc1 = 0.f;
    for (int p = base; p < end; ++p) {
        int s = srcs[p];
        s = ((unsigned)s < (unsigned)N) ? s : 0;
        float z = a_s[s] + adn;
        z = z > 0.f ? z : NEG_SLOPE * z;
        float w = __expf(z - mn);
        acc0 += w * b2f(h1[(size_t)s * 512 + c]);
        acc1 += w * b2f(h1[(size_t)s * 512 + c + 256]);
    }
    size_t rb = (size_t)n * 512;
    float v0 = acc0 * inv + b2f(hl1[rb + c]);
    float v1 = acc1 * inv + b2f(hl1[rb + c + 256]);
    hl1[rb + c]       = f2b(fmaxf(v0, 0.f));
    hl1[rb + c + 256] = f2b(fmaxf(v1, 0.f));
}

// ---------------------------------------------------------------------------
// layer-2 aggregation (256-wide) + residual add
// ---------------------------------------------------------------------------
__global__ __launch_bounds__(256)
void k_agg2(const u16* h, const int* off, const int* srcs,
            const float* a_s, const float* a_d, const float* mx, const float* ssum,
            const u16* add, u16* out, int N)
{
    int n = blockIdx.x;
    int base = off[n], end = off[n + 1];
    float adn = a_d[n], mn = mx[n];
    float inv = 1.f / (ssum[n] + 1e-16f);
    int c = threadIdx.x;
    float acc = 0.f;
    for (int p = base; p < end; ++p) {
        int s = srcs[p];
        s = ((unsigned)s < (unsigned)N) ? s : 0;
        float z = a_s[s] + adn;
        z = z > 0.f ? z : NEG_SLOPE * z;
        float w = __expf(z - mn);
        acc += w * b2f(h[(size_t)s * 256 + c]);
    }
    float v = acc * inv + b2f(add[(size_t)n * 256 + c]);
    out[(size_t)n * 256 + c] = f2b(v);
}

// ---------------------------------------------------------------------------
// naive GEMM, fp32 A [M,256] @ fp32 B [256,512] (+biases) -> bf16 C [M,512]
// ---------------------------------------------------------------------------
__global__ __launch_bounds__(256)
void ngemmF(const float* A, const float* B, const float* bias1, const float* bias2,
            u16* C, int M, int relu)
{
    __shared__ float As[8][256];
    const int row0 = blockIdx.x * 8;
    const int colb = blockIdx.y * 256;
    const int t = threadIdx.x;
    for (int i = t; i < 2048; i += 256) {
        int r = i >> 8, c = i & 255;
        int n = row0 + r;
        As[r][c] = (n < M) ? A[(size_t)n * 256 + c] : 0.f;
    }
    __syncthreads();
    float acc[8] = {};
    const int col = colb + t;
    for (int k = 0; k < 256; ++k) {
        float bv = B[(size_t)k * 512 + col];
        #pragma unroll
        for (int r = 0; r < 8; ++r) acc[r] += As[r][k] * bv;
    }
    float bb = (bias1 ? bias1[col] : 0.f) + (bias2 ? bias2[col] : 0.f);
    #pragma unroll
    for (int r = 0; r < 8; ++r) {
        int n = row0 + r;
        if (n < M) {
            float v = acc[r] + bb;
            if (relu) v = fmaxf(v, 0.f);
            C[(size_t)n * 512 + col] = f2b(v);
        }
    }
}

// ---------------------------------------------------------------------------
// naive GEMM, bf16 A [M,K] @ fp32 B [K,256] (+biases) -> bf16 C [M,256]
// in-place safe (C==A)
// ---------------------------------------------------------------------------
template<int K>
__global__ __launch_bounds__(256)
void ngemmB(const u16* A, const float* B, const float* bias1, const float* bias2,
            u16* C, int M, int relu)
{
    __shared__ float As[8][K];
    const int row0 = blockIdx.x * 8;
    const int t = threadIdx.x;
    for (int i = t; i < 8 * K; i += 256) {
        int r = i / K, c = i % K;
        int n = row0 + r;
        As[r][c] = (n < M) ? b2f(A[(size_t)n * K + c]) : 0.f;
    }
    __syncthreads();
    float acc[8] = {};
    const int col = t;
    for (int k = 0; k < K; ++k) {
        float bv = B[(size_t)k * 256 + col];
        #pragma unroll
        for (int r = 0; r < 8; ++r) acc[r] += As[r][k] * bv;
    }
    float bb = (bias1 ? bias1[col] : 0.f) + (bias2 ? bias2[col] : 0.f);
    #pragma unroll
    for (int r = 0; r < 8; ++r) {
        int n = row0 + r;
        if (n < M) {
            float v = acc[r] + bb;
            if (relu) v = fmaxf(v, 0.f);
            C[(size_t)n * 256 + col] = f2b(v);
        }
    }
}

// ---------------------------------------------------------------------------
// classifier + softmax: one wave per node, 256 -> 5, FP32 OUTPUT
// ---------------------------------------------------------------------------
__global__ __launch_bounds__(64)
void k_fc_softmax(const u16* hin, const float* fcw, const float* fcb,
                  float* out, int N)
{
    int n = blockIdx.x;
    int lane = threadIdx.x;
    const u16* hr = hin + (size_t)n * 256;
    int k0 = lane * 4;
    float hv[4];
    float p[5] = {0.f, 0.f, 0.f, 0.f, 0.f};
    #pragma unroll
    for (int j = 0; j < 4; ++j) hv[j] = b2f(hr[k0 + j]);
    #pragma unroll
    for (int j = 0; j < 4; ++j) {
        const float* wr = fcw + (size_t)(k0 + j) * 5;
        #pragma unroll
        for (int c = 0; c < 5; ++c) p[c] += hv[j] * wr[c];
    }
    #pragma unroll
    for (int c = 0; c < 5; ++c) {
        #pragma unroll
        for (int s = 32; s; s >>= 1) p[c] += __shfl_xor(p[c], s, 64);
    }
    if (lane == 0) {
        float m = -1e30f;
        #pragma unroll
        for (int c = 0; c < 5; ++c) { p[c] += fcb[c]; m = fmaxf(m, p[c]); }
        float s = 0.f, e[5];
        #pragma unroll
        for (int c = 0; c < 5; ++c) { e[c] = __expf(p[c] - m); s += e[c]; }
        float inv = 1.f / s;
        #pragma unroll
        for (int c = 0; c < 5; ++c) out[(size_t)n * 5 + c] = e[c] * inv;
    }
}

// ---------------------------------------------------------------------------
extern "C" void kernel_launch(void* const* d_in, const int* in_sizes, int n_in,
                              void* d_out, int out_size, void* d_ws, size_t ws_size,
                              hipStream_t stream)
{
    const float* x    = (const float*)d_in[0];
    const int*   ei   = (const int*)  d_in[1];
    const float* W1   = (const float*)d_in[2];
    const float* as1  = (const float*)d_in[3];
    const float* ad1  = (const float*)d_in[4];
    const float* bc1  = (const float*)d_in[5];
    const float* A1w  = (const float*)d_in[6];
    const float* b1   = (const float*)d_in[7];
    const float* W2   = (const float*)d_in[8];
    const float* as2  = (const float*)d_in[9];
    const float* ad2  = (const float*)d_in[10];
    const float* bc2  = (const float*)d_in[11];
    const float* A2w  = (const float*)d_in[12];
    const float* b2   = (const float*)d_in[13];
    const float* Hw1  = (const float*)d_in[14];
    const float* Hb1  = (const float*)d_in[15];
    const float* Hw2  = (const float*)d_in[16];
    const float* Hb2  = (const float*)d_in[17];
    const float* Hw3  = (const float*)d_in[18];
    const float* Hb3  = (const float*)d_in[19];
    const float* fcw  = (const float*)d_in[20];
    const float* fcb  = (const float*)d_in[21];
    float* out = (float*)d_out;          // <-- fp32 output (reference dtype)

    const int D = 256;
    const int N = in_sizes[0] / D;
    const int E = in_sizes[1] / 2;

    char* w = (char*)d_ws;
    auto alloc = [&](size_t bytes) {
        char* p = w;
        w += (bytes + 255) & ~(size_t)255;
        return p;
    };
    int*   flag   = (int*)  alloc(256);
    int*   flag64 = (int*)  alloc(256);
    float* a_s    = (float*)alloc((size_t)N * 4);
    float* a_d    = (float*)alloc((size_t)N * 4);
    float* mx     = (float*)alloc((size_t)N * 4);
    float* ssum   = (float*)alloc((size_t)N * 4);
    int*   deg    = (int*)  alloc((size_t)N * 4);
    int*   cursor = (int*)  alloc((size_t)N * 4);
    int*   offA   = (int*)  alloc((size_t)(N + 1) * 4);
    int*   srcs   = (int*)  alloc((size_t)E * 4);
    u16*   BUF1   = (u16*)  alloc((size_t)N * 512 * 2);  // h1 -> h2|res2
    u16*   BUF2   = (u16*)  alloc((size_t)N * 512 * 2);  // pre/hl1 -> out2/MLP

    // src32/dst32 alias BUF1 (dead before h1 is written)
    int* src32 = (int*)BUF1;
    int* dst32 = src32 + E;

    size_t need = (size_t)(w - (char*)d_ws);
    if (ws_size < need) {
        float code = 1000.0f + (float)(ws_size >> 20);
        k_diag<<<(out_size + 255) / 256, 256, 0, stream>>>(out, out_size, code);
        return;
    }

    const int EB  = (E + 255) / 256;
    const int NB4 = (N + 3) / 4;
    const int OB  = (out_size + 255) / 256;
    const int NE  = (N > E ? N : E);
    const size_t NH2 = (size_t)N * 256;

    hipMemsetAsync(flag, 0, 4, stream);

    // ---- edge extraction + CSR by destination ----
    k_detect <<<1, 256, 0, stream>>>(ei, E, flag64);
    k_extract<<<EB, 256, 0, stream>>>(ei, E, flag64, src32, dst32);
    hipMemsetAsync(deg, 0, (size_t)N * 4, stream);
    k_count  <<<EB, 256, 0, stream>>>(dst32, deg, E, N);
    k_scan   <<<1, 1024, 0, stream>>>(deg, offA, cursor, N, E);
    k_scatter<<<EB, 256, 0, stream>>>(src32, dst32, cursor, srcs, E, N);
    scan_csr <<<(NE + 255) / 256, 256, 0, stream>>>(offA, srcs, N, E, flag, 1);

    // ---- h1 = x @ W1 (bf16; overwrites src32/dst32 region, already dead) ----
    dim3 gF((N + 7) / 8, 2);
    ngemmF<<<gF, 256, 0, stream>>>(x, W1, nullptr, nullptr, BUF1, N, 0);

    // ---- direct attention coefficients (reference mirror) ----
    k_rowdot2<<<NB4, 256, 0, stream>>>(BUF1, 512, 512, as1, ad1, a_s, a_d, N);

    // ---- layer-1 softmax stats + pre-residual + aggregation ----
    k_alpha<<<NB4, 256, 0, stream>>>(offA, srcs, a_s, a_d, mx, ssum, N);
    ngemmF<<<gF, 256, 0, stream>>>(x, A1w, b1, bc1, BUF2, N, 0);   // pre = x@A1+b1+bc1
    k_agg1<<<N, 256, 0, stream>>>(BUF1, offA, srcs, a_s, a_d, mx, ssum, BUF2, N);

    // ---- layer 2: h2 = hl1@W2 ; res2 = hl1@A2+b2+bc2 (into BUF1) ----
    dim3 gB((N + 7) / 8, 1);
    ngemmB<512><<<gB, 256, 0, stream>>>(BUF2, W2, nullptr, nullptr, BUF1, N, 0);
    ngemmB<512><<<gB, 256, 0, stream>>>(BUF2, A2w, b2, bc2, BUF1 + NH2, N, 0);

    k_rowdot2<<<NB4, 256, 0, stream>>>(BUF1, 256, 256, as2, ad2, a_s, a_d, N);
    k_alpha<<<NB4, 256, 0, stream>>>(offA, srcs, a_s, a_d, mx, ssum, N);
    k_agg2<<<N, 256, 0, stream>>>(BUF1, offA, srcs, a_s, a_d, mx, ssum,
                                  BUF1 + NH2, BUF2, N);

    // ---- MLP 3x [256->256] relu, in-place in BUF2 ----
    ngemmB<256><<<gB, 256, 0, stream>>>(BUF2, Hw1, Hb1, nullptr, BUF2, N, 1);
    ngemmB<256><<<gB, 256, 0, stream>>>(BUF2, Hw2, Hb2, nullptr, BUF2, N, 1);
    ngemmB<256><<<gB, 256, 0, stream>>>(BUF2, Hw3, Hb3, nullptr, BUF2, N, 1);

    // ---- classifier + softmax (fp32 out) ----
    k_fc_softmax<<<N, 64, 0, stream>>>(BUF2, fcw, fcb, out, N);
    scan_out<<<OB, 256, 0, stream>>>(out, out_size, flag, 2);

    k_final_diag<<<OB, 256, 0, stream>>>(flag, out, out_size);
}

// Round 10
// 1216.616 us; speedup vs baseline: 1.8247x; 1.8247x over previous
//
#include <hip/hip_runtime.h>

typedef unsigned short u16;
typedef short short8 __attribute__((ext_vector_type(8)));
typedef float float4v __attribute__((ext_vector_type(4)));

#define NEG_SLOPE 0.2f

static __device__ __forceinline__ float b2f(u16 u) {
    union { unsigned int i; float f; } x; x.i = ((unsigned int)u) << 16; return x.f;
}
static __device__ __forceinline__ u16 f2b(float f) {
    unsigned int u = __float_as_uint(f);
    unsigned int r = (u + 0x7fffu + ((u >> 16) & 1u)) >> 16;
    return (u16)r;
}

// ---------------------------------------------------------------------------
// diagnostics: code 32 = CSR inconsistent; 1000+ = ws too small
// ---------------------------------------------------------------------------
__global__ void k_diag(float* out, int n, float val)
{
    int i = blockIdx.x * 256 + threadIdx.x;
    if (i < n) out[i] = val;
}

__global__ void scan_csr(const int* off, const int* srcs, int N, int E,
                         int* flag, int bit)
{
    int i = blockIdx.x * 256 + threadIdx.x;
    if (i < N) {
        int a = off[i], b = off[i + 1];
        if (a < 0 || b < a || b > E) atomicOr(flag, bit);
    }
    if (i == 0 && off[N] != E) atomicOr(flag, bit);
    if (i < E) {
        if ((unsigned)srcs[i] >= (unsigned)N) atomicOr(flag, bit);
    }
}

__global__ void k_final_diag(const int* flag, float* out, int n)
{
    int f = *flag;
    if (f == 0) return;
    int b = __ffs(f) - 1;
    float val = 32.0f * (b + 1);
    int i = blockIdx.x * 256 + threadIdx.x;
    if (i < n) out[i] = val;
}

// ---------------------------------------------------------------------------
// edge_index dtype probe + canonical int32 extraction
// ---------------------------------------------------------------------------
__global__ void k_detect(const int* ei, int E, int* flag64)
{
    __shared__ int zc;
    if (threadIdx.x == 0) zc = 0;
    __syncthreads();
    int idx = 1 + 2 * (int)threadIdx.x;
    int z = (idx < 2 * E && ei[idx] == 0) ? 1 : 0;
    atomicAdd(&zc, z);
    __syncthreads();
    if (threadIdx.x == 0) *flag64 = (zc >= 200) ? 1 : 0;
}

__global__ void k_extract(const int* ei, int E, const int* flag64,
                          int* src, int* dst)
{
    int e = blockIdx.x * 256 + threadIdx.x;
    if (e >= E) return;
    if (*flag64) {
        src[e] = ei[2 * e];
        dst[e] = ei[2 * E + 2 * e];
    } else {
        src[e] = ei[e];
        dst[e] = ei[E + e];
    }
}

// ---------------------------------------------------------------------------
// CSR construction (bound-checked)
// ---------------------------------------------------------------------------
__global__ void k_count(const int* dst, int* deg, int E, int N)
{
    int e = blockIdx.x * 256 + threadIdx.x;
    if (e < E) {
        int d = dst[e];
        if ((unsigned)d < (unsigned)N) atomicAdd(&deg[d], 1);
    }
}

__global__ __launch_bounds__(1024)
void k_scan(const int* deg, int* off, int* cursor, int N, int E)
{
    __shared__ int sd[1024];
    __shared__ int running;
    int tid = threadIdx.x;
    if (tid == 0) running = 0;
    __syncthreads();
    for (int base = 0; base < N; base += 1024) {
        int i = base + tid;
        int v = (i < N) ? deg[i] : 0;
        sd[tid] = v;
        __syncthreads();
        for (int s = 1; s < 1024; s <<= 1) {
            int t = (tid >= s) ? sd[tid - s] : 0;
            __syncthreads();
            sd[tid] += t;
            __syncthreads();
        }
        int excl = sd[tid] - v + running;
        if (i < N) { off[i] = excl; cursor[i] = excl; }
        int total = sd[1023];
        __syncthreads();
        if (tid == 0) running += total;
        __syncthreads();
    }
    if (tid == 0) off[N] = E;
}

__global__ void k_scatter(const int* src, const int* dst, int* cursor,
                          int* srcs, int E, int N)
{
    int e = blockIdx.x * 256 + threadIdx.x;
    if (e < E) {
        int d = dst[e];
        if ((unsigned)d < (unsigned)N) {
            int p = atomicAdd(&cursor[d], 1);
            if ((unsigned)p < (unsigned)E) srcs[p] = src[e];
        }
    }
}

// ---------------------------------------------------------------------------
// direct row-dot on bf16 h against two fp32 vectors — one wave per node
// ---------------------------------------------------------------------------
__global__ __launch_bounds__(256)
void k_rowdot2(const u16* h, int ld, int H, const float* vs, const float* vd,
               float* a_s, float* a_d, int N)
{
    int wave = threadIdx.x >> 6, lane = threadIdx.x & 63;
    int n = blockIdx.x * 4 + wave;
    if (n >= N) return;
    const u16* hr = h + (size_t)n * ld;
    float ss = 0.f, sd = 0.f;
    for (int i = lane; i < H; i += 64) {
        float v = b2f(hr[i]);
        ss += v * vs[i];
        sd += v * vd[i];
    }
    #pragma unroll
    for (int m = 32; m; m >>= 1) {
        ss += __shfl_xor(ss, m, 64);
        sd += __shfl_xor(sd, m, 64);
    }
    if (lane == 0) { a_s[n] = ss; a_d[n] = sd; }
}

// ---------------------------------------------------------------------------
// per-dst softmax stats
// ---------------------------------------------------------------------------
__global__ __launch_bounds__(256)
void k_alpha(const int* off, const int* srcs, const float* a_s, const float* a_d,
             float* mx, float* ssum, int N)
{
    int wave = threadIdx.x >> 6, lane = threadIdx.x & 63;
    int n = blockIdx.x * 4 + wave;
    if (n >= N) return;
    int base = off[n], end = off[n + 1];
    float adn = a_d[n];
    float m = -1e30f;
    for (int p = base + lane; p < end; p += 64) {
        int s = srcs[p];
        s = ((unsigned)s < (unsigned)N) ? s : 0;
        float z = a_s[s] + adn;
        z = z > 0.f ? z : NEG_SLOPE * z;
        m = fmaxf(m, z);
    }
    #pragma unroll
    for (int s = 32; s; s >>= 1) m = fmaxf(m, __shfl_xor(m, s, 64));
    float sum = 0.f;
    for (int p = base + lane; p < end; p += 64) {
        int s = srcs[p];
        s = ((unsigned)s < (unsigned)N) ? s : 0;
        float z = a_s[s] + adn;
        z = z > 0.f ? z : NEG_SLOPE * z;
        sum += __expf(z - m);
    }
    #pragma unroll
    for (int s = 32; s; s >>= 1) sum += __shfl_xor(sum, s, 64);
    if (lane == 0) { mx[n] = m; ssum[n] = sum; }
}

// ---------------------------------------------------------------------------
// layer-1 aggregation, 512-wide: hl1 = relu(agg(h1)/ssum + pre), in-place pre
// ---------------------------------------------------------------------------
__global__ __launch_bounds__(256)
void k_agg1(const u16* h1, const int* off, const int* srcs,
            const float* a_s, const float* a_d, const float* mx, const float* ssum,
            u16* hl1, int N)
{
    int n = blockIdx.x;
    int base = off[n], end = off[n + 1];
    float adn = a_d[n], mn = mx[n];
    float inv = 1.f / (ssum[n] + 1e-16f);
    int c = threadIdx.x;
    float acc0 = 0.f, acc1 = 0.f;
    for (int p = base; p < end; ++p) {
        int s = srcs[p];
        s = ((unsigned)s < (unsigned)N) ? s : 0;
        float z = a_s[s] + adn;
        z = z > 0.f ? z : NEG_SLOPE * z;
        float w = __expf(z - mn);
        acc0 += w * b2f(h1[(size_t)s * 512 + c]);
        acc1 += w * b2f(h1[(size_t)s * 512 + c + 256]);
    }
    size_t rb = (size_t)n * 512;
    float v0 = acc0 * inv + b2f(hl1[rb + c]);
    float v1 = acc1 * inv + b2f(hl1[rb + c + 256]);
    hl1[rb + c]       = f2b(fmaxf(v0, 0.f));
    hl1[rb + c + 256] = f2b(fmaxf(v1, 0.f));
}

// ---------------------------------------------------------------------------
// layer-2 aggregation (256-wide) + residual add
// ---------------------------------------------------------------------------
__global__ __launch_bounds__(256)
void k_agg2(const u16* h, const int* off, const int* srcs,
            const float* a_s, const float* a_d, const float* mx, const float* ssum,
            const u16* add, u16* out, int N)
{
    int n = blockIdx.x;
    int base = off[n], end = off[n + 1];
    float adn = a_d[n], mn = mx[n];
    float inv = 1.f / (ssum[n] + 1e-16f);
    int c = threadIdx.x;
    float acc = 0.f;
    for (int p = base; p < end; ++p) {
        int s = srcs[p];
        s = ((unsigned)s < (unsigned)N) ? s : 0;
        float z = a_s[s] + adn;
        z = z > 0.f ? z : NEG_SLOPE * z;
        float w = __expf(z - mn);
        acc += w * b2f(h[(size_t)s * 256 + c]);
    }
    float v = acc * inv + b2f(add[(size_t)n * 256 + c]);
    out[(size_t)n * 256 + c] = f2b(v);
}

// ---------------------------------------------------------------------------
// MFMA GEMM, 64x64 tile, BK=32. A: fp32 (AF32) or bf16; B: fp32 weights.
// Both converted to bf16 during LDS staging. C bf16 [M,NC] (+fp32 biases,
// optional relu). Out-of-place only.
// ---------------------------------------------------------------------------
template<bool AF32>
__global__ __launch_bounds__(256)
void gemm64(const void* Ap, const float* B, const float* bias1, const float* bias2,
            u16* C, int M, int K, int NC, int relu)
{
    __shared__ u16 As[64][40];
    __shared__ u16 Bs[64][40];   // transposed: Bs[n][k]

    const int tid  = threadIdx.x;
    const int wave = tid >> 6;
    const int lane = tid & 63;
    const int rowBase = blockIdx.x * 64;
    const int colBase = blockIdx.y * 64;

    float4v acc[4] = {};
    const int ar = tid >> 2;          // 0..63
    const int ac = (tid & 3) * 8;     // 0,8,16,24
    const int bk = tid >> 3;          // 0..31
    const int bn = (tid & 7) * 8;     // 0..56
    const int m16 = lane & 15;
    const int q = lane >> 4;

    for (int k0 = 0; k0 < K; k0 += 32) {
        __syncthreads();
        {   // stage A 64x32
            int grow = rowBase + ar;
            if (AF32) {
                const float* Af = (const float*)Ap;
                float4 v0 = {0,0,0,0}, v1 = {0,0,0,0};
                if (grow < M) {
                    const float* p = Af + (size_t)grow * K + k0 + ac;
                    v0 = *(const float4*)p;
                    v1 = *(const float4*)(p + 4);
                }
                u16* d = &As[ar][ac];
                d[0]=f2b(v0.x); d[1]=f2b(v0.y); d[2]=f2b(v0.z); d[3]=f2b(v0.w);
                d[4]=f2b(v1.x); d[5]=f2b(v1.y); d[6]=f2b(v1.z); d[7]=f2b(v1.w);
            } else {
                const u16* Ab = (const u16*)Ap;
                int4 v = {0, 0, 0, 0};
                if (grow < M) v = *(const int4*)(Ab + (size_t)grow * K + k0 + ac);
                *(int4*)&As[ar][ac] = v;
            }
        }
        {   // stage B 32x64 fp32 -> bf16, transposed
            const float* bp = B + (size_t)(k0 + bk) * NC + colBase + bn;
            float4 w0 = *(const float4*)bp;
            float4 w1 = *(const float4*)(bp + 4);
            u16 t[8] = {f2b(w0.x), f2b(w0.y), f2b(w0.z), f2b(w0.w),
                        f2b(w1.x), f2b(w1.y), f2b(w1.z), f2b(w1.w)};
            #pragma unroll
            for (int j = 0; j < 8; ++j) Bs[bn + j][bk] = t[j];
        }
        __syncthreads();

        short8 aF = *(const short8*)&As[wave * 16 + m16][q * 8];
        #pragma unroll
        for (int c = 0; c < 4; ++c) {
            short8 bF = *(const short8*)&Bs[c * 16 + m16][q * 8];
            acc[c] = __builtin_amdgcn_mfma_f32_16x16x32_bf16(aF, bF, acc[c], 0, 0, 0);
        }
    }

    #pragma unroll
    for (int c = 0; c < 4; ++c) {
        int gcol = colBase + c * 16 + m16;
        float bv = (bias1 ? bias1[gcol] : 0.f) + (bias2 ? bias2[gcol] : 0.f);
        #pragma unroll
        for (int i = 0; i < 4; ++i) {
            int grow = rowBase + wave * 16 + q * 4 + i;
            if (grow < M) {
                float v = acc[c][i] + bv;
                if (relu) v = fmaxf(v, 0.f);
                C[(size_t)grow * NC + gcol] = f2b(v);
            }
        }
    }
}

// ---------------------------------------------------------------------------
// MFMA full-row-width GEMM (BM=64, K=NC=256), in-place safe (C==A):
// one block owns 64 rows entirely; A bf16, B fp32 (staged->bf16), bias fp32.
// ---------------------------------------------------------------------------
__global__ __launch_bounds__(256)
void rowfull256(const u16* A, const float* B, const float* bias,
                u16* C, int M, int relu)
{
    __shared__ u16 As[64][40];
    __shared__ u16 Bs[256][40];

    const int tid  = threadIdx.x;
    const int wave = tid >> 6;
    const int lane = tid & 63;
    const int rowBase = blockIdx.x * 64;
    const int m16 = lane & 15;
    const int q = lane >> 4;

    float4v acc[16] = {};
    const int ar = tid >> 2, ac = (tid & 3) * 8;
    const int bk = tid >> 3, bn0 = (tid & 7) * 8;

    for (int k0 = 0; k0 < 256; k0 += 32) {
        __syncthreads();
        {
            int grow = rowBase + ar;
            int4 v = {0, 0, 0, 0};
            if (grow < M) v = *(const int4*)(A + (size_t)grow * 256 + k0 + ac);
            *(int4*)&As[ar][ac] = v;
        }
        #pragma unroll
        for (int j8 = 0; j8 < 4; ++j8) {
            int bn = bn0 + j8 * 64;
            const float* bp = B + (size_t)(k0 + bk) * 256 + bn;
            float4 w0 = *(const float4*)bp;
            float4 w1 = *(const float4*)(bp + 4);
            u16 t[8] = {f2b(w0.x), f2b(w0.y), f2b(w0.z), f2b(w0.w),
                        f2b(w1.x), f2b(w1.y), f2b(w1.z), f2b(w1.w)};
            #pragma unroll
            for (int j = 0; j < 8; ++j) Bs[bn + j][bk] = t[j];
        }
        __syncthreads();

        short8 aF = *(const short8*)&As[wave * 16 + m16][q * 8];
        #pragma unroll
        for (int c = 0; c < 16; ++c) {
            short8 bF = *(const short8*)&Bs[c * 16 + m16][q * 8];
            acc[c] = __builtin_amdgcn_mfma_f32_16x16x32_bf16(aF, bF, acc[c], 0, 0, 0);
        }
    }

    #pragma unroll
    for (int c = 0; c < 16; ++c) {
        int col = c * 16 + m16;
        float bv = bias ? bias[col] : 0.f;
        #pragma unroll
        for (int i = 0; i < 4; ++i) {
            int grow = rowBase + wave * 16 + q * 4 + i;
            if (grow < M) {
                float v = acc[c][i] + bv;
                if (relu) v = fmaxf(v, 0.f);
                C[(size_t)grow * 256 + col] = f2b(v);
            }
        }
    }
}

// ---------------------------------------------------------------------------
// classifier + softmax: one wave per node, 256 -> 5, fp32 output
// ---------------------------------------------------------------------------
__global__ __launch_bounds__(64)
void k_fc_softmax(const u16* hin, const float* fcw, const float* fcb,
                  float* out, int N)
{
    int n = blockIdx.x;
    int lane = threadIdx.x;
    const u16* hr = hin + (size_t)n * 256;
    int k0 = lane * 4;
    float hv[4];
    float p[5] = {0.f, 0.f, 0.f, 0.f, 0.f};
    #pragma unroll
    for (int j = 0; j < 4; ++j) hv[j] = b2f(hr[k0 + j]);
    #pragma unroll
    for (int j = 0; j < 4; ++j) {
        const float* wr = fcw + (size_t)(k0 + j) * 5;
        #pragma unroll
        for (int c = 0; c < 5; ++c) p[c] += hv[j] * wr[c];
    }
    #pragma unroll
    for (int c = 0; c < 5; ++c) {
        #pragma unroll
        for (int s = 32; s; s >>= 1) p[c] += __shfl_xor(p[c], s, 64);
    }
    if (lane == 0) {
        float m = -1e30f;
        #pragma unroll
        for (int c = 0; c < 5; ++c) { p[c] += fcb[c]; m = fmaxf(m, p[c]); }
        float s = 0.f, e[5];
        #pragma unroll
        for (int c = 0; c < 5; ++c) { e[c] = __expf(p[c] - m); s += e[c]; }
        float inv = 1.f / s;
        #pragma unroll
        for (int c = 0; c < 5; ++c) out[(size_t)n * 5 + c] = e[c] * inv;
    }
}

// ---------------------------------------------------------------------------
extern "C" void kernel_launch(void* const* d_in, const int* in_sizes, int n_in,
                              void* d_out, int out_size, void* d_ws, size_t ws_size,
                              hipStream_t stream)
{
    const float* x    = (const float*)d_in[0];
    const int*   ei   = (const int*)  d_in[1];
    const float* W1   = (const float*)d_in[2];
    const float* as1  = (const float*)d_in[3];
    const float* ad1  = (const float*)d_in[4];
    const float* bc1  = (const float*)d_in[5];
    const float* A1w  = (const float*)d_in[6];
    const float* b1   = (const float*)d_in[7];
    const float* W2   = (const float*)d_in[8];
    const float* as2  = (const float*)d_in[9];
    const float* ad2  = (const float*)d_in[10];
    const float* bc2  = (const float*)d_in[11];
    const float* A2w  = (const float*)d_in[12];
    const float* b2   = (const float*)d_in[13];
    const float* Hw1  = (const float*)d_in[14];
    const float* Hb1  = (const float*)d_in[15];
    const float* Hw2  = (const float*)d_in[16];
    const float* Hb2  = (const float*)d_in[17];
    const float* Hw3  = (const float*)d_in[18];
    const float* Hb3  = (const float*)d_in[19];
    const float* fcw  = (const float*)d_in[20];
    const float* fcb  = (const float*)d_in[21];
    float* out = (float*)d_out;

    const int D = 256;
    const int N = in_sizes[0] / D;
    const int E = in_sizes[1] / 2;

    char* w = (char*)d_ws;
    auto alloc = [&](size_t bytes) {
        char* p = w;
        w += (bytes + 255) & ~(size_t)255;
        return p;
    };
    int*   flag   = (int*)  alloc(256);
    int*   flag64 = (int*)  alloc(256);
    float* a_s    = (float*)alloc((size_t)N * 4);
    float* a_d    = (float*)alloc((size_t)N * 4);
    float* mx     = (float*)alloc((size_t)N * 4);
    float* ssum   = (float*)alloc((size_t)N * 4);
    int*   deg    = (int*)  alloc((size_t)N * 4);
    int*   cursor = (int*)  alloc((size_t)N * 4);
    int*   offA   = (int*)  alloc((size_t)(N + 1) * 4);
    int*   srcs   = (int*)  alloc((size_t)E * 4);
    u16*   BUF1   = (u16*)  alloc((size_t)N * 512 * 2);  // h1 -> h2|res2
    u16*   BUF2   = (u16*)  alloc((size_t)N * 512 * 2);  // pre/hl1 -> out2/MLP

    // src32/dst32 alias BUF1 (dead before h1 is written)
    int* src32 = (int*)BUF1;
    int* dst32 = src32 + E;

    size_t need = (size_t)(w - (char*)d_ws);             // ~107 MB (proven fits)
    if (ws_size < need) {
        float code = 1000.0f + (float)(ws_size >> 20);
        k_diag<<<(out_size + 255) / 256, 256, 0, stream>>>(out, out_size, code);
        return;
    }

    const int EB  = (E + 255) / 256;
    const int NB4 = (N + 3) / 4;
    const int OB  = (out_size + 255) / 256;
    const int NE  = (N > E ? N : E);
    const int RB64 = (N + 63) / 64;
    const size_t NH2 = (size_t)N * 256;

    hipMemsetAsync(flag, 0, 4, stream);

    // ---- edge extraction + CSR by destination ----
    k_detect <<<1, 256, 0, stream>>>(ei, E, flag64);
    k_extract<<<EB, 256, 0, stream>>>(ei, E, flag64, src32, dst32);
    hipMemsetAsync(deg, 0, (size_t)N * 4, stream);
    k_count  <<<EB, 256, 0, stream>>>(dst32, deg, E, N);
    k_scan   <<<1, 1024, 0, stream>>>(deg, offA, cursor, N, E);
    k_scatter<<<EB, 256, 0, stream>>>(src32, dst32, cursor, srcs, E, N);
    scan_csr <<<(NE + 255) / 256, 256, 0, stream>>>(offA, srcs, N, E, flag, 1);

    // ---- h1 = x @ W1 (MFMA; overwrites src32/dst32 region, already dead) ----
    dim3 g512(RB64, 8);
    gemm64<true><<<g512, 256, 0, stream>>>(x, W1, nullptr, nullptr,
                                           BUF1, N, 256, 512, 0);

    // ---- attention coefficients + softmax stats (layer 1) ----
    k_rowdot2<<<NB4, 256, 0, stream>>>(BUF1, 512, 512, as1, ad1, a_s, a_d, N);
    k_alpha<<<NB4, 256, 0, stream>>>(offA, srcs, a_s, a_d, mx, ssum, N);

    // ---- pre = x@A1 + b1 + bc1 ; hl1 = relu(agg(h1) + pre) (in-place) ----
    gemm64<true><<<g512, 256, 0, stream>>>(x, A1w, b1, bc1,
                                           BUF2, N, 256, 512, 0);
    k_agg1<<<N, 256, 0, stream>>>(BUF1, offA, srcs, a_s, a_d, mx, ssum, BUF2, N);

    // ---- layer 2: h2 = hl1@W2 ; res2 = hl1@A2 + b2 + bc2 ----
    dim3 g256(RB64, 4);
    gemm64<false><<<g256, 256, 0, stream>>>(BUF2, W2, nullptr, nullptr,
                                            BUF1, N, 512, 256, 0);
    gemm64<false><<<g256, 256, 0, stream>>>(BUF2, A2w, b2, bc2,
                                            BUF1 + NH2, N, 512, 256, 0);

    k_rowdot2<<<NB4, 256, 0, stream>>>(BUF1, 256, 256, as2, ad2, a_s, a_d, N);
    k_alpha<<<NB4, 256, 0, stream>>>(offA, srcs, a_s, a_d, mx, ssum, N);
    k_agg2<<<N, 256, 0, stream>>>(BUF1, offA, srcs, a_s, a_d, mx, ssum,
                                  BUF1 + NH2, BUF2, N);

    // ---- MLP 3x [256->256] relu, in-place in BUF2 (MFMA rowfull) ----
    rowfull256<<<RB64, 256, 0, stream>>>(BUF2, Hw1, Hb1, BUF2, N, 1);
    rowfull256<<<RB64, 256, 0, stream>>>(BUF2, Hw2, Hb2, BUF2, N, 1);
    rowfull256<<<RB64, 256, 0, stream>>>(BUF2, Hw3, Hb3, BUF2, N, 1);

    // ---- classifier + softmax (fp32 out) ----
    k_fc_softmax<<<N, 64, 0, stream>>>(BUF2, fcw, fcb, out, N);

    k_final_diag<<<OB, 256, 0, stream>>>(flag, out, out_size);
}